// Round 8
// baseline (123.899 us; speedup 1.0000x reference)
//
#include <hip/hip_runtime.h>

typedef __attribute__((ext_vector_type(8))) short short8;
typedef __attribute__((ext_vector_type(4))) float float4v;

// Window tile range for kept-block i: win(i) = clamped 4-row window (H=16, PART=4).
// BOTH passes use this table: s2 keeps row-block hr, reduces hc in win(hr);
// s1 keeps col-block hc, reduces hr in win(hc). In each pass's (transposed) view
// the reduced tile range is win(kept block) = [LOW, HIW].
__constant__ int LOW[16] = {0,0,0,1,2,3,4,5,6,7,8,9,10,11,12,12};
__constant__ int HIW[16] = {3,3,3,4,5,6,7,8,9,10,11,12,13,14,15,15};

__device__ __forceinline__ unsigned short f2bf(float f) {
    unsigned int x = __builtin_bit_cast(unsigned int, f);
    x += 0x7FFF + ((x >> 16) & 1);   // round-to-nearest-even
    return (unsigned short)(x >> 16);
}

struct __align__(16) U16x8 { unsigned short u[8]; };

// Max across the 16 lanes of a DPP row (laneM) — pure VALU, no LDS pipe.
template <int CTRL>
__device__ __forceinline__ float dppmaxf(float x) {
    int y = __builtin_amdgcn_update_dpp(0, __builtin_bit_cast(int, x),
                                        CTRL, 0xF, 0xF, true);
    return fmaxf(x, __builtin_bit_cast(float, y));
}
__device__ __forceinline__ float rowmax16(float x) {
    x = dppmaxf<0xB1>(x);    // quad_perm [1,0,3,2]  (xor 1)
    x = dppmaxf<0x4E>(x);    // quad_perm [2,3,0,1]  (xor 2)
    x = dppmaxf<0x141>(x);   // row_half_mirror      (xor 4 within 8)
    x = dppmaxf<0x140>(x);   // row_mirror           (xor 8 within 16)
    return x;
}

// Kernel 0: f32 [img][64c][256s] -> bf16 [img][s][c] with chunk XOR swizzle
// (chunk' = (c/8) ^ (s%8)). imgs 0..47 = probe, 48..95 = gallery.
__global__ __launch_bounds__(256) void pretranspose_kernel(
    const float* __restrict__ prob,
    const float* __restrict__ gal,
    unsigned short* __restrict__ outT)   // [96][16384] bf16
{
    const int img = blockIdx.x;
    const float* src = (img < 48) ? (prob + img * 16384)
                                  : (gal + (img - 48) * 16384);
    unsigned short* dst = outT + img * 16384;
    const int tid = threadIdx.x;
    const int c0 = (tid & 7) * 8;
    const int s0 = (tid >> 3) * 8;
    unsigned short v[8][8];
#pragma unroll
    for (int i = 0; i < 8; ++i) {
        const float* p = src + (c0 + i) * 256 + s0;
        const float4v f0 = *(const float4v*)(p);
        const float4v f1 = *(const float4v*)(p + 4);
        v[i][0] = f2bf(f0.x); v[i][1] = f2bf(f0.y);
        v[i][2] = f2bf(f0.z); v[i][3] = f2bf(f0.w);
        v[i][4] = f2bf(f1.x); v[i][5] = f2bf(f1.y);
        v[i][6] = f2bf(f1.z); v[i][7] = f2bf(f1.w);
    }
#pragma unroll
    for (int j = 0; j < 8; ++j) {
        U16x8 o;
#pragma unroll
        for (int i = 0; i < 8; ++i) o.u[i] = v[i][j];
        const int srow = s0 + j;
        const int off = srow * 64 + (((c0 >> 3) ^ (srow & 7)) << 3);
        *(U16x8*)(dst + off) = o;
    }
}

// Kernel A: one block per (probe, gallery) pair. Two mirrored row-max passes,
// fragments straight from L2-resident pre-transposed global images. Per pass,
// ALL fragment loads (8 A + 14 B) are issued up-front (fixed 7-trip padded
// range, clamped duplicate loads) so each wave keeps ~22 loads in flight
// (vs depth-1 prefetch's ~3) — memory-level parallelism is the bottleneck.
//   pass 0 (s2): A = gallery rows, B = probe;   kept = hr
//   pass 1 (s1): A = probe rows,   B = gallery; kept = hc
// acc.i = score(row = rt*16 + q*4 + i, col = ct*16 + laneM) in the pass's view.
__global__ __launch_bounds__(256, 4) void score_pam_kernel(
    const unsigned short* __restrict__ preT,  // [96][16384] bf16 pre-transposed
    const float* __restrict__ fcw,            // [256] f32
    float* __restrict__ outDot,               // [2304]
    float* __restrict__ outSum,               // [2304]
    float* __restrict__ outSq)                // [2304]
{
    __shared__ float red[4][4][4];             // (w, q, {dot,sum,sq,pad})

    const int tid = threadIdx.x;
    const int pair = blockIdx.x;
    const int ip = pair / 48;
    const int ig = pair % 48;
    const unsigned short* pimg = preT + ip * 16384;
    const unsigned short* gimg = preT + (48 + ig) * 16384;

    const int lane = tid & 63;
    const int w = tid >> 6;
    const int laneM = lane & 15;
    const int q = lane >> 4;
    const int z = laneM & 7;

    int lo[4], hi[4];
#pragma unroll
    for (int j = 0; j < 4; ++j) { lo[j] = LOW[4 * w + j]; hi[j] = HIW[4 * w + j]; }
    const int ct0 = lo[0];
    const int ctmax = hi[3];

    // per-pass row maxes, kept across both passes:
    // rm[pass][j][i] for row rt=4w+j, sub-row i — folded into scalars at end.
    float rmax[2][4][4];

    for (int pass = 0; pass < 2; ++pass) {
        const unsigned short* Aimg = pass ? pimg : gimg;
        const unsigned short* Bimg = pass ? gimg : pimg;

        // ---- issue ALL loads up-front: 8 A-frags + 14 B-frags (padded to 7 ct)
        short8 a0[4], a1[4];
#pragma unroll
        for (int j = 0; j < 4; ++j) {
            const int srow = (4 * w + j) * 16 + laneM;
            a0[j] = *(const short8*)(Aimg + srow * 64 + ((q ^ z) << 3));
            a1[j] = *(const short8*)(Aimg + srow * 64 + (((q + 4) ^ z) << 3));
        }
        short8 B0[7], B1[7];
#pragma unroll
        for (int i = 0; i < 7; ++i) {
            int ct = ct0 + i;
            if (ct > ctmax) ct = ctmax;    // clamped duplicate (L1-hit, harmless)
            const int sl = ct * 16 + laneM;
            B0[i] = *(const short8*)(Bimg + sl * 64 + ((q ^ z) << 3));
            B1[i] = *(const short8*)(Bimg + sl * 64 + (((q + 4) ^ z) << 3));
        }

        float4v run[4];
#pragma unroll
        for (int j = 0; j < 4; ++j)
            run[j] = (float4v){ -3.0e38f, -3.0e38f, -3.0e38f, -3.0e38f };

        // ---- compute: first MFMA only waits for B0[0]/B1[0]; rest stay in flight
#pragma unroll
        for (int i = 0; i < 7; ++i) {
            const int ct = ct0 + i;    // padded iteration: all j-conditions false
#pragma unroll
            for (int j = 0; j < 4; ++j) {
                if (ct >= lo[j] && ct <= hi[j]) {
                    float4v acc = { 0.f, 0.f, 0.f, 0.f };
                    acc = __builtin_amdgcn_mfma_f32_16x16x32_bf16(a0[j], B0[i], acc, 0, 0, 0);
                    acc = __builtin_amdgcn_mfma_f32_16x16x32_bf16(a1[j], B1[i], acc, 0, 0, 0);
                    run[j].x = fmaxf(run[j].x, acc.x);
                    run[j].y = fmaxf(run[j].y, acc.y);
                    run[j].z = fmaxf(run[j].z, acc.z);
                    run[j].w = fmaxf(run[j].w, acc.w);
                }
            }
        }

        // row-max across the 16 column lanes (DPP, VALU-only)
#pragma unroll
        for (int j = 0; j < 4; ++j) {
            rmax[pass][j][0] = rowmax16(run[j].x);
            rmax[pass][j][1] = rowmax16(run[j].y);
            rmax[pass][j][2] = rowmax16(run[j].z);
            rmax[pass][j][3] = rowmax16(run[j].w);
        }
    }

    // ---- epilogue: fc_w loaded only now (keeps loop VGPR pressure down)
    float dot = 0.f, sum = 0.f, sq = 0.f;
    const float msk = (laneM == 0) ? 1.0f : 0.0f;   // count each row once
#pragma unroll
    for (int j = 0; j < 4; ++j) {
        const float4v fw = *(const float4v*)(fcw + (4 * w + j) * 16 + q * 4);
#pragma unroll
        for (int p = 0; p < 2; ++p) {
            float t;
            t = msk * rmax[p][j][0]; dot += t * fw.x; sum += t; sq += t * rmax[p][j][0];
            t = msk * rmax[p][j][1]; dot += t * fw.y; sum += t; sq += t * rmax[p][j][1];
            t = msk * rmax[p][j][2]; dot += t * fw.z; sum += t; sq += t * rmax[p][j][2];
            t = msk * rmax[p][j][3]; dot += t * fw.w; sum += t; sq += t * rmax[p][j][3];
        }
    }

    if (laneM == 0) {   // lanes 0,16,32,48 of each wave hold disjoint row sets
        red[w][q][0] = dot; red[w][q][1] = sum; red[w][q][2] = sq;
    }
    __syncthreads();
    if (tid < 3) {
        float s = 0.f;
#pragma unroll
        for (int a = 0; a < 4; ++a)
#pragma unroll
            for (int b = 0; b < 4; ++b) s += red[a][b][tid];
        if (tid == 0) outDot[pair] = s;
        else if (tid == 1) outSum[pair] = s;
        else outSq[pair] = s;
    }
}

// Kernel B: single block. Global BN1 stats from per-pair sums, fc (linear),
// pair-sum, BN2 over 2304, sigmoid, f32 store.
__global__ __launch_bounds__(256) void finalize_kernel(
    const float* __restrict__ dDot,
    const float* __restrict__ dSum,
    const float* __restrict__ dSq,
    const float* __restrict__ bng,
    const float* __restrict__ bnb,
    const float* __restrict__ fcw,
    const float* __restrict__ fcb,
    const float* __restrict__ lg,
    const float* __restrict__ lb,
    float* __restrict__ outp)   // [2304] f32
{
    __shared__ float red[12];
    const int tid = threadIdx.x;
    const int lane = tid & 63;
    const int w = tid >> 6;

    float S = 0.f, Q = 0.f;
    float dv[9];
#pragma unroll
    for (int k = 0; k < 9; ++k) {
        const int i = tid + 256 * k;
        dv[k] = dDot[i];
        S += dSum[i];
        Q += dSq[i];
    }
    float Wj = fcw[tid];
#pragma unroll
    for (int d = 32; d >= 1; d >>= 1) {
        S += __shfl_down(S, d, 64);
        Q += __shfl_down(Q, d, 64);
        Wj += __shfl_down(Wj, d, 64);
    }
    if (lane == 0) { red[w] = S; red[4 + w] = Q; red[8 + w] = Wj; }
    __syncthreads();
    S = red[0] + red[1] + red[2] + red[3];
    Q = red[4] + red[5] + red[6] + red[7];
    const float W = red[8] + red[9] + red[10] + red[11];
    __syncthreads();

    const float N1 = 1179648.0f;           // 4608 * 256 elements in BN1
    const float m1 = S / N1;
    const float v1 = Q / N1 - m1 * m1;     // biased var (torch training default)
    const float inv1 = rsqrtf(v1 + 1e-5f);
    const float g1 = bng[0], b1 = bnb[0], fb = fcb[0];
    const float g2 = lg[0], b2 = lb[0];
    const float cA = g1 * inv1;
    const float cB = 2.f * (b1 * W + fb) - cA * 2.f * m1 * W;

    float Sy = 0.f, Qy = 0.f;
    float yv[9];
#pragma unroll
    for (int k = 0; k < 9; ++k) {
        const float y = cA * dv[k] + cB;
        yv[k] = y;
        Sy += y;
        Qy += y * y;
    }
#pragma unroll
    for (int d = 32; d >= 1; d >>= 1) {
        Sy += __shfl_down(Sy, d, 64);
        Qy += __shfl_down(Qy, d, 64);
    }
    if (lane == 0) { red[w] = Sy; red[4 + w] = Qy; }
    __syncthreads();
    Sy = red[0] + red[1] + red[2] + red[3];
    Qy = red[4] + red[5] + red[6] + red[7];

    const float m2 = Sy / 2304.0f;
    const float v2 = Qy / 2304.0f - m2 * m2;
    const float inv2 = rsqrtf(v2 + 1e-5f);
#pragma unroll
    for (int k = 0; k < 9; ++k) {
        const int i = tid + 256 * k;
        const float z = g2 * (yv[k] - m2) * inv2 + b2;
        outp[i] = 1.0f / (1.0f + __expf(-z));
    }
}

extern "C" void kernel_launch(void* const* d_in, const int* in_sizes, int n_in,
                              void* d_out, int out_size, void* d_ws, size_t ws_size,
                              hipStream_t stream) {
    const float* prob = (const float*)d_in[0];
    const float* gal  = (const float*)d_in[1];
    const float* bng  = (const float*)d_in[2];
    const float* bnb  = (const float*)d_in[3];
    const float* fcw  = (const float*)d_in[4];
    const float* fcb  = (const float*)d_in[5];
    const float* lg   = (const float*)d_in[6];
    const float* lb   = (const float*)d_in[7];

    unsigned short* preT = (unsigned short*)d_ws;        // 96*16384 bf16 = 3 MB
    float* ws = (float*)((char*)d_ws + 96 * 16384 * sizeof(unsigned short));
    float* dDot = ws;            // [2304]
    float* dSum = ws + 2304;     // [2304]
    float* dSq  = ws + 4608;     // [2304]

    hipLaunchKernelGGL(pretranspose_kernel, dim3(96), dim3(256), 0, stream,
                       prob, gal, preT);
    hipLaunchKernelGGL(score_pam_kernel, dim3(48 * 48), dim3(256), 0, stream,
                       preT, fcw, dDot, dSum, dSq);
    hipLaunchKernelGGL(finalize_kernel, dim3(1), dim3(256), 0, stream,
                       dDot, dSum, dSq, bng, bnb, fcw, fcb, lg, lb,
                       (float*)d_out);
}

// Round 9
// 97.905 us; speedup vs baseline: 1.2655x; 1.2655x over previous
//
#include <hip/hip_runtime.h>

typedef __attribute__((ext_vector_type(8))) short short8;
typedef __attribute__((ext_vector_type(4))) float float4v;

// win(i) = clamped 4-wide tile window [LOW[i], HIW[i]] (H=16, PART=4).
// Padded to 24 entries with never-true sentinels so the fixed 8-trip padded
// ct-loop can index LOW/HIW with raw ct (<= 17) and get FALSE conditions.
__constant__ int LOW[24] = {0,0,0,1,2,3,4,5,6,7,8,9,10,11,12,12,
                            99,99,99,99,99,99,99,99};
__constant__ int HIW[24] = {3,3,3,4,5,6,7,8,9,10,11,12,13,14,15,15,
                            -1,-1,-1,-1,-1,-1,-1,-1};
// Per-wave ct-loop start: wave w owns row-tiles rt=4w..4w+3; its union ct range
// (s2: ct in win(rt); s1: rt in win(ct)) is [CTLO[w], CTLO[w]+5..7] subset of 8 trips.
__constant__ int CTLO[4] = {0, 2, 6, 10};

__device__ __forceinline__ unsigned short f2bf(float f) {
    unsigned int x = __builtin_bit_cast(unsigned int, f);
    x += 0x7FFF + ((x >> 16) & 1);   // round-to-nearest-even
    return (unsigned short)(x >> 16);
}

struct __align__(16) U16x8 { unsigned short u[8]; };

// Max across the 16 lanes of a DPP row (laneM) — pure VALU, no LDS pipe.
template <int CTRL>
__device__ __forceinline__ float dppmaxf(float x) {
    int y = __builtin_amdgcn_update_dpp(0, __builtin_bit_cast(int, x),
                                        CTRL, 0xF, 0xF, true);
    return fmaxf(x, __builtin_bit_cast(float, y));
}
__device__ __forceinline__ float rowmax16(float x) {
    x = dppmaxf<0xB1>(x);    // quad_perm [1,0,3,2]  (xor 1)
    x = dppmaxf<0x4E>(x);    // quad_perm [2,3,0,1]  (xor 2)
    x = dppmaxf<0x141>(x);   // row_half_mirror      (xor 4 within 8)
    x = dppmaxf<0x140>(x);   // row_mirror           (xor 8 within 16)
    return x;
}

// Kernel 0: f32 [img][64c][256s] -> bf16 [img][s][c] with chunk XOR swizzle
// (chunk' = (c/8) ^ (s%8)). imgs 0..47 = probe, 48..95 = gallery.
__global__ __launch_bounds__(256) void pretranspose_kernel(
    const float* __restrict__ prob,
    const float* __restrict__ gal,
    unsigned short* __restrict__ outT)   // [96][16384] bf16
{
    const int img = blockIdx.x;
    const float* src = (img < 48) ? (prob + img * 16384)
                                  : (gal + (img - 48) * 16384);
    unsigned short* dst = outT + img * 16384;
    const int tid = threadIdx.x;
    const int c0 = (tid & 7) * 8;
    const int s0 = (tid >> 3) * 8;
    unsigned short v[8][8];
#pragma unroll
    for (int i = 0; i < 8; ++i) {
        const float* p = src + (c0 + i) * 256 + s0;
        const float4v f0 = *(const float4v*)(p);
        const float4v f1 = *(const float4v*)(p + 4);
        v[i][0] = f2bf(f0.x); v[i][1] = f2bf(f0.y);
        v[i][2] = f2bf(f0.z); v[i][3] = f2bf(f0.w);
        v[i][4] = f2bf(f1.x); v[i][5] = f2bf(f1.y);
        v[i][6] = f2bf(f1.z); v[i][7] = f2bf(f1.w);
    }
#pragma unroll
    for (int j = 0; j < 8; ++j) {
        U16x8 o;
#pragma unroll
        for (int i = 0; i < 8; ++i) o.u[i] = v[i][j];
        const int srow = s0 + j;
        const int off = srow * 64 + (((c0 >> 3) ^ (srow & 7)) << 3);
        *(U16x8*)(dst + off) = o;
    }
}

// Kernel A: one block per (probe, gallery) pair. SINGLE pass over the 78-tile
// union (tile (hr,hc) computed once, feeding BOTH maxes):
//   s2 (keep row r): running per-lane max -> DPP rowmax16 at end.
//   s1 (keep col s): per-tile 4-fmax fold to quad-partial col-max, held in 8
//       registers (s1p[i], i = ct - CTLO[w]); one small LDS merge per block.
// A = gallery rows (m = laneM), B = probe cols, straight from L2-hot preT.
// acc.i = score(r = rt*16 + q*4 + i, s = ct*16 + laneM).
__global__ __launch_bounds__(256, 4) void score_pam_kernel(
    const unsigned short* __restrict__ preT,  // [96][16384] bf16 pre-transposed
    const float* __restrict__ fcw,            // [256] f32
    float* __restrict__ outDot,               // [2304]
    float* __restrict__ outSum,               // [2304]
    float* __restrict__ outSq)                // [2304]
{
    __shared__ float s1part[4][8][4][16];      // (w, i, q, col) 8 KB
    __shared__ float redA[4][4][4];            // s2: (w, q, {dot,sum,sq,pad})
    __shared__ float redB[4][4];               // s1: (w, {dot,sum,sq,pad})

    const int tid = threadIdx.x;
    const int pair = blockIdx.x;
    const int ip = pair / 48;
    const int ig = pair % 48;
    const unsigned short* pimg = preT + ip * 16384;         // B: probe (cols)
    const unsigned short* gimg = preT + (48 + ig) * 16384;  // A: gallery (rows)

    const int lane = tid & 63;
    const int w = tid >> 6;
    const int laneM = lane & 15;
    const int q = lane >> 4;
    const int z = laneM & 7;

    const int rtb = 4 * w;
    int lo2[4], hi2[4];
#pragma unroll
    for (int j = 0; j < 4; ++j) { lo2[j] = LOW[rtb + j]; hi2[j] = HIW[rtb + j]; }
    const int ctbase = CTLO[w];

    // A-fragments: this wave's 4 gallery row-tiles (8 loads, L2-hot)
    short8 a0[4], a1[4];
#pragma unroll
    for (int j = 0; j < 4; ++j) {
        const int srow = (rtb + j) * 16 + laneM;
        a0[j] = *(const short8*)(gimg + srow * 64 + ((q ^ z) << 3));
        a1[j] = *(const short8*)(gimg + srow * 64 + (((q + 4) ^ z) << 3));
    }

    float4v run[4];
#pragma unroll
    for (int j = 0; j < 4; ++j)
        run[j] = (float4v){ -3.0e38f, -3.0e38f, -3.0e38f, -3.0e38f };
    float s1p[8];
#pragma unroll
    for (int i = 0; i < 8; ++i) s1p[i] = -3.0e38f;

    // ---- single union ct-loop: fixed 8 trips (padded), conditions on RAW ct
#pragma unroll
    for (int i = 0; i < 8; ++i) {
        const int ctr = ctbase + i;              // raw (may exceed 15: padded)
        const int ctc = (ctr > 15) ? 15 : ctr;   // clamped for the address only
        const int sl = ctc * 16 + laneM;
        const short8 b0 = *(const short8*)(pimg + sl * 64 + ((q ^ z) << 3));
        const short8 b1 = *(const short8*)(pimg + sl * 64 + (((q + 4) ^ z) << 3));
        const int wl = LOW[ctr], wh = HIW[ctr];  // sentinel rows for ctr > 15
#pragma unroll
        for (int j = 0; j < 4; ++j) {
            const int rt = rtb + j;
            const bool c2 = (ctr >= lo2[j]) && (ctr <= hi2[j]);  // hc in win(hr)
            const bool c1 = (rt >= wl) && (rt <= wh);            // hr in win(hc)
            if (c1 || c2) {
                float4v acc = { 0.f, 0.f, 0.f, 0.f };
                acc = __builtin_amdgcn_mfma_f32_16x16x32_bf16(a0[j], b0, acc, 0, 0, 0);
                acc = __builtin_amdgcn_mfma_f32_16x16x32_bf16(a1[j], b1, acc, 0, 0, 0);
                if (c2) {   // s2: per-row running max (row = q*4+comp, col = laneM)
                    run[j].x = fmaxf(run[j].x, acc.x);
                    run[j].y = fmaxf(run[j].y, acc.y);
                    run[j].z = fmaxf(run[j].z, acc.z);
                    run[j].w = fmaxf(run[j].w, acc.w);
                }
                if (c1) {   // s1: quad-partial col-max (fold this quad's 4 rows)
                    const float t = fmaxf(fmaxf(acc.x, acc.y), fmaxf(acc.z, acc.w));
                    s1p[i] = fmaxf(s1p[i], t);
                }
            }
        }
    }

    // ---- s2 epilogue: DPP row-max + masked register accumulation
    float dot = 0.f, sum = 0.f, sq = 0.f;
    const float msk = (laneM == 0) ? 1.0f : 0.0f;   // count each row once
#pragma unroll
    for (int j = 0; j < 4; ++j) {
        const float rx = rowmax16(run[j].x);
        const float ry = rowmax16(run[j].y);
        const float rz = rowmax16(run[j].z);
        const float rw = rowmax16(run[j].w);
        const float4v fw = *(const float4v*)(fcw + (rtb + j) * 16 + q * 4);
        float t;
        t = msk * rx; dot += t * fw.x; sum += t; sq += t * rx;
        t = msk * ry; dot += t * fw.y; sum += t; sq += t * ry;
        t = msk * rz; dot += t * fw.z; sum += t; sq += t * rz;
        t = msk * rw; dot += t * fw.w; sum += t; sq += t * rw;
    }
    if (laneM == 0) { redA[w][q][0] = dot; redA[w][q][1] = sum; redA[w][q][2] = sq; }

    // ---- publish s1 quad-partials (2-way bank aliasing only: free)
#pragma unroll
    for (int i = 0; i < 8; ++i) s1part[w][i][q][laneM] = s1p[i];
    __syncthreads();

    // ---- s1 merge: thread tid <-> (hc = tid>>4, col = tid&15); flat s = tid
    {
        const int hc = tid >> 4;
        const int col = tid & 15;
        float v = -3.0e38f;
#pragma unroll
        for (int wv = 0; wv < 4; ++wv) {
            const int ii = hc - CTLO[wv];
            if (ii >= 0 && ii < 8) {
#pragma unroll
                for (int q2 = 0; q2 < 4; ++q2)
                    v = fmaxf(v, s1part[wv][ii][q2][col]);
            }
        }
        float d1 = v * fcw[tid];
        float s1v = v;
        float q1 = v * v;
#pragma unroll
        for (int d = 32; d >= 1; d >>= 1) {
            d1 += __shfl_down(d1, d, 64);
            s1v += __shfl_down(s1v, d, 64);
            q1 += __shfl_down(q1, d, 64);
        }
        if (lane == 0) { redB[w][0] = d1; redB[w][1] = s1v; redB[w][2] = q1; }
    }
    __syncthreads();

    if (tid < 3) {
        float s = 0.f;
#pragma unroll
        for (int a = 0; a < 4; ++a) {
#pragma unroll
            for (int b = 0; b < 4; ++b) s += redA[a][b][tid];
            s += redB[a][tid];
        }
        if (tid == 0) outDot[pair] = s;
        else if (tid == 1) outSum[pair] = s;
        else outSq[pair] = s;
    }
}

// Kernel B: single block. Global BN1 stats from per-pair sums, fc (linear),
// pair-sum, BN2 over 2304, sigmoid, f32 store.
__global__ __launch_bounds__(256) void finalize_kernel(
    const float* __restrict__ dDot,
    const float* __restrict__ dSum,
    const float* __restrict__ dSq,
    const float* __restrict__ bng,
    const float* __restrict__ bnb,
    const float* __restrict__ fcw,
    const float* __restrict__ fcb,
    const float* __restrict__ lg,
    const float* __restrict__ lb,
    float* __restrict__ outp)   // [2304] f32
{
    __shared__ float red[12];
    const int tid = threadIdx.x;
    const int lane = tid & 63;
    const int w = tid >> 6;

    float S = 0.f, Q = 0.f;
    float dv[9];
#pragma unroll
    for (int k = 0; k < 9; ++k) {
        const int i = tid + 256 * k;
        dv[k] = dDot[i];
        S += dSum[i];
        Q += dSq[i];
    }
    float Wj = fcw[tid];
#pragma unroll
    for (int d = 32; d >= 1; d >>= 1) {
        S += __shfl_down(S, d, 64);
        Q += __shfl_down(Q, d, 64);
        Wj += __shfl_down(Wj, d, 64);
    }
    if (lane == 0) { red[w] = S; red[4 + w] = Q; red[8 + w] = Wj; }
    __syncthreads();
    S = red[0] + red[1] + red[2] + red[3];
    Q = red[4] + red[5] + red[6] + red[7];
    const float W = red[8] + red[9] + red[10] + red[11];
    __syncthreads();

    const float N1 = 1179648.0f;           // 4608 * 256 elements in BN1
    const float m1 = S / N1;
    const float v1 = Q / N1 - m1 * m1;     // biased var (torch training default)
    const float inv1 = rsqrtf(v1 + 1e-5f);
    const float g1 = bng[0], b1 = bnb[0], fb = fcb[0];
    const float g2 = lg[0], b2 = lb[0];
    const float cA = g1 * inv1;
    const float cB = 2.f * (b1 * W + fb) - cA * 2.f * m1 * W;

    float Sy = 0.f, Qy = 0.f;
    float yv[9];
#pragma unroll
    for (int k = 0; k < 9; ++k) {
        const float y = cA * dv[k] + cB;
        yv[k] = y;
        Sy += y;
        Qy += y * y;
    }
#pragma unroll
    for (int d = 32; d >= 1; d >>= 1) {
        Sy += __shfl_down(Sy, d, 64);
        Qy += __shfl_down(Qy, d, 64);
    }
    if (lane == 0) { red[w] = Sy; red[4 + w] = Qy; }
    __syncthreads();
    Sy = red[0] + red[1] + red[2] + red[3];
    Qy = red[4] + red[5] + red[6] + red[7];

    const float m2 = Sy / 2304.0f;
    const float v2 = Qy / 2304.0f - m2 * m2;
    const float inv2 = rsqrtf(v2 + 1e-5f);
#pragma unroll
    for (int k = 0; k < 9; ++k) {
        const int i = tid + 256 * k;
        const float z = g2 * (yv[k] - m2) * inv2 + b2;
        outp[i] = 1.0f / (1.0f + __expf(-z));
    }
}

extern "C" void kernel_launch(void* const* d_in, const int* in_sizes, int n_in,
                              void* d_out, int out_size, void* d_ws, size_t ws_size,
                              hipStream_t stream) {
    const float* prob = (const float*)d_in[0];
    const float* gal  = (const float*)d_in[1];
    const float* bng  = (const float*)d_in[2];
    const float* bnb  = (const float*)d_in[3];
    const float* fcw  = (const float*)d_in[4];
    const float* fcb  = (const float*)d_in[5];
    const float* lg   = (const float*)d_in[6];
    const float* lb   = (const float*)d_in[7];

    unsigned short* preT = (unsigned short*)d_ws;        // 96*16384 bf16 = 3 MB
    float* ws = (float*)((char*)d_ws + 96 * 16384 * sizeof(unsigned short));
    float* dDot = ws;            // [2304]
    float* dSum = ws + 2304;     // [2304]
    float* dSq  = ws + 4608;     // [2304]

    hipLaunchKernelGGL(pretranspose_kernel, dim3(96), dim3(256), 0, stream,
                       prob, gal, preT);
    hipLaunchKernelGGL(score_pam_kernel, dim3(48 * 48), dim3(256), 0, stream,
                       preT, fcw, dDot, dSum, dSq);
    hipLaunchKernelGGL(finalize_kernel, dim3(1), dim3(256), 0, stream,
                       dDot, dSum, dSq, bng, bnb, fcw, fcb, lg, lb,
                       (float*)d_out);
}